// Round 3
// baseline (136.717 us; speedup 1.0000x reference)
//
#include <hip/hip_runtime.h>
#include <stdint.h>

#define UNITS 1024
#define BATCH 4096
#define FOURU 4096

typedef __bf16 bf16x8 __attribute__((ext_vector_type(8)));
typedef float f32x4 __attribute__((ext_vector_type(4)));

// round-to-nearest-even f32 -> bf16
__device__ __forceinline__ uint16_t f2bf(float f) {
  uint32_t u = __builtin_bit_cast(uint32_t, f);
  u += 0x7FFFu + ((u >> 16) & 1u);
  return (uint16_t)(u >> 16);
}
__device__ __forceinline__ float bf2f(uint16_t b) {
  uint32_t u = ((uint32_t)b) << 16;
  return __builtin_bit_cast(float, u);
}
__device__ __forceinline__ float fsig(float x) {
  return 1.0f / (1.0f + __expf(-x));
}
__device__ __forceinline__ f32x4 mfma16x16x32(bf16x8 a, bf16x8 b, f32x4 c) {
  return __builtin_amdgcn_mfma_f32_16x16x32_bf16(a, b, c, 0, 0, 0);
}

// async global->LDS, 16B per lane; LDS dest is wave-uniform base + lane*16
__device__ __forceinline__ void gll16(uint16_t* lds, const uint16_t* g) {
  __builtin_amdgcn_global_load_lds(
      (const __attribute__((address_space(1))) uint32_t*)g,
      (__attribute__((address_space(3))) uint32_t*)lds, 16, 0, 0);
}

// Stage a [ROWS x 64k] bf16 tile into LDS as TWO k-half sub-tiles:
//   granules [0, ROWS*4)        = rows' k in [0,32)   (row-major [ROWS][32])
//   granules [ROWS*4, ROWS*8)   = rows' k in [32,64)
// LDS dest stays linear (gload_lds requirement); the k-half split lives in
// the per-lane GLOBAL source address. Row stride inside a half = 64B ->
// conflict-free ds_read_b128 fragment reads (round-2-verified pattern).
template <int ROWS>
__device__ __forceinline__ void stage64(const uint16_t* __restrict__ src,
                                        uint16_t* lds, int tid) {
  const int wb = tid & 192;  // wave*64 granules
#pragma unroll
  for (int p = 0; p < ROWS / 32; ++p) {
    const int gi = p * 256 + tid;
    const int h = gi / (ROWS * 4);         // k-half (0 or 1)
    const int r = (gi >> 2) & (ROWS - 1);  // row within half
    const int kg = gi & 3;                 // 8-elem group within half
    gll16(lds + (p * 256 + wb) * 8, src + r * UNITS + h * 32 + kg * 8);
  }
}

// ---- prep (fused): blocks [0,4096): h f32->bf16; [4096,8192): R -> RT bf16 ----
__global__ __launch_bounds__(256) void prep_kernel(const float* __restrict__ h32,
                                                   uint16_t* __restrict__ hbf,
                                                   const float* __restrict__ R,
                                                   uint16_t* __restrict__ RT) {
  __shared__ float t[32][33];
  const int b = blockIdx.x;
  if (b < 4096) {
    const int i = (b * 256 + threadIdx.x) * 4;
    float4 v = *(const float4*)(h32 + i);
    ushort4 o;
    o.x = f2bf(v.x); o.y = f2bf(v.y); o.z = f2bf(v.z); o.w = f2bf(v.w);
    *(ushort4*)(hbf + i) = o;
  } else {
    const int bb = b - 4096;
    const int n0 = (bb & 127) * 32, k0 = (bb >> 7) * 32;
    const int tx = threadIdx.x & 31, ty = threadIdx.x >> 5;
#pragma unroll
    for (int i = 0; i < 4; ++i)
      t[ty + i * 8][tx] = R[(size_t)(k0 + ty + i * 8) * FOURU + n0 + tx];
    __syncthreads();
#pragma unroll
    for (int i = 0; i < 4; ++i)
      RT[(size_t)(n0 + ty + i * 8) * UNITS + k0 + tx] = f2bf(t[tx][ty + i * 8]);
  }
}

// ---- unified GEMM core: C = A(bf16,[4096][1024]) @ BT^T, BK=64, dbuf, gll ----
// EPI 0: s1, N=2048 (z cols [0,1024), r cols [1024,2048)) -> zb / rhb
// EPI 1: s2, hh=tanh(+ch+b1); hn=z*h+(1-z)*hh -> h_out(f32) + hnb(bf16)
// EPI 2: s3, o =tanh(+co+b2) -> o_out(f32)
template <int BN, int EPI>
__global__ __launch_bounds__(256, 2) void gemm_kernel(
    const uint16_t* __restrict__ abf, const uint16_t* __restrict__ bt,
    const int* __restrict__ idx, const float* __restrict__ kc,
    const float* __restrict__ bz, const float* __restrict__ bias,
    const float* __restrict__ h32, const uint16_t* __restrict__ zb_in,
    float* __restrict__ out32, uint16_t* __restrict__ outbf,
    uint16_t* __restrict__ out2bf) {
  constexpr int NF = BN / 32;  // B frags per wave per k-half
  __shared__ uint16_t sA[2][128 * 64];
  __shared__ uint16_t sB[2][BN * 64];
  const int tid = threadIdx.x;
  const int lane = tid & 63, wave = tid >> 6;
  const int l15 = lane & 15, l4 = lane >> 4;
  const int row0 = blockIdx.y * 128, col0 = blockIdx.x * BN;
  const int rb = (wave >> 1) * 64, cb = (wave & 1) * (BN / 2);
  const uint16_t* pa = abf + (size_t)row0 * UNITS;
  const uint16_t* pb = bt + (size_t)col0 * UNITS;
  f32x4 acc[4][NF] = {};

  stage64<128>(pa, sA[0], tid);
  stage64<BN>(pb, sB[0], tid);
  __syncthreads();

  int cur = 0;
  for (int t = 0; t < UNITS / 64; ++t) {
    if (t < UNITS / 64 - 1) {  // issue next-tile loads before compute
      stage64<128>(pa + (t + 1) * 64, sA[cur ^ 1], tid);
      stage64<BN>(pb + (t + 1) * 64, sB[cur ^ 1], tid);
    }
    const bf16x8* A8 = (const bf16x8*)sA[cur];
    const bf16x8* B8 = (const bf16x8*)sB[cur];
#pragma unroll
    for (int h = 0; h < 2; ++h) {
      bf16x8 af[4], bf[NF];
#pragma unroll
      for (int m = 0; m < 4; ++m)
        af[m] = A8[h * 128 * 4 + (rb + m * 16 + l15) * 4 + l4];
#pragma unroll
      for (int n = 0; n < NF; ++n)
        bf[n] = B8[h * BN * 4 + (cb + n * 16 + l15) * 4 + l4];
#pragma unroll
      for (int m = 0; m < 4; ++m)
#pragma unroll
        for (int n = 0; n < NF; ++n)
          acc[m][n] = mfma16x16x32(af[m], bf[n], acc[m][n]);
    }
    __syncthreads();  // drains next-tile gload_lds; fences buffer swap
    cur ^= 1;
  }

#pragma unroll
  for (int m = 0; m < 4; ++m) {
#pragma unroll
    for (int q = 0; q < 4; ++q) {
      const int i = row0 + rb + m * 16 + l4 * 4 + q;
      const int ch = idx[i];
      const float* kcrow = kc + (size_t)ch * FOURU;
#pragma unroll
      for (int n = 0; n < NF; ++n) {
        const int jc = col0 + cb + n * 16 + l15;
        const float a = acc[m][n][q];
        if (EPI == 0) {
          if (jc < UNITS) {  // z gate (uniform per block: col0 multiple of 128)
            float z = fsig(a + kcrow[jc] + bz[jc]);
            outbf[(size_t)i * UNITS + jc] = f2bf(z);
          } else {  // r gate
            const int j = jc - UNITS;
            const size_t ij = (size_t)i * UNITS + j;
            float r = fsig(a + kcrow[jc] + bias[j]);
            out2bf[ij] = f2bf(r * h32[ij]);
          }
        } else if (EPI == 1) {
          const size_t ij = (size_t)i * UNITS + jc;
          float hh = tanhf(a + kcrow[2 * UNITS + jc] + bias[UNITS + jc]);
          float z = bf2f(zb_in[ij]);
          float hv = h32[ij];
          float hn = z * hv + (1.0f - z) * hh;
          out32[ij] = hn;
          outbf[ij] = f2bf(hn);
        } else {
          const size_t ij = (size_t)i * UNITS + jc;
          out32[ij] = tanhf(a + kcrow[3 * UNITS + jc] + bias[2 * UNITS + jc]);
        }
      }
    }
  }
}

extern "C" void kernel_launch(void* const* d_in, const int* in_sizes, int n_in,
                              void* d_out, int out_size, void* d_ws, size_t ws_size,
                              hipStream_t stream) {
  const int* idx = (const int*)d_in[0];
  const float* h32 = (const float*)d_in[1];
  const float* R = (const float*)d_in[2];
  const float* kc = (const float*)d_in[3];
  const float* bz = (const float*)d_in[4];
  const float* bias = (const float*)d_in[5];

  float* o_out = (float*)d_out;                  // 4M f32 (output o)
  float* h_out = o_out + (size_t)BATCH * UNITS;  // 4M f32 (output h)

  uint16_t* hbf = (uint16_t*)d_ws;               // bf16(h_tm1)   8 MB
  uint16_t* rt = hbf + (size_t)BATCH * UNITS;    // bf16(R^T)     8 MB
  uint16_t* rhb = rt + (size_t)FOURU * UNITS;    // bf16(r*h)     8 MB
  uint16_t* hnb = rhb + (size_t)BATCH * UNITS;   // bf16(h_new)   8 MB
  uint16_t* zbuf = hnb + (size_t)BATCH * UNITS;  // bf16(z)       8 MB

  prep_kernel<<<dim3(8192), 256, 0, stream>>>(h32, hbf, R, rt);

  // s1: N=2048 unified z|r GEMM, BN=128 -> grid (16,32)=512
  gemm_kernel<128, 0><<<dim3(16, 32), 256, 0, stream>>>(
      hbf, rt, idx, kc, bz, bias, h32, nullptr, nullptr, zbuf, rhb);

  // s2: N=1024, BN=64 -> grid (16,32)=512
  gemm_kernel<64, 1><<<dim3(16, 32), 256, 0, stream>>>(
      rhb, rt + (size_t)2 * UNITS * UNITS, idx, kc, bz, bias, h32, zbuf,
      h_out, hnb, nullptr);

  // s3: N=1024, BN=64 -> grid (16,32)=512
  gemm_kernel<64, 2><<<dim3(16, 32), 256, 0, stream>>>(
      hnb, rt + (size_t)3 * UNITS * UNITS, idx, kc, bz, bias, nullptr, nullptr,
      o_out, nullptr, nullptr);
}

// Round 4
// 107.883 us; speedup vs baseline: 1.2673x; 1.2673x over previous
//
#include <hip/hip_runtime.h>
#include <stdint.h>

#define UNITS 1024
#define BATCH 4096
#define FOURU 4096

typedef __bf16 bf16x8 __attribute__((ext_vector_type(8)));
typedef float f32x4 __attribute__((ext_vector_type(4)));

// round-to-nearest-even f32 -> bf16
__device__ __forceinline__ uint16_t f2bf(float f) {
  uint32_t u = __builtin_bit_cast(uint32_t, f);
  u += 0x7FFFu + ((u >> 16) & 1u);
  return (uint16_t)(u >> 16);
}
__device__ __forceinline__ float bf2f(uint16_t b) {
  uint32_t u = ((uint32_t)b) << 16;
  return __builtin_bit_cast(float, u);
}
__device__ __forceinline__ float fsig(float x) {
  return 1.0f / (1.0f + __expf(-x));
}
__device__ __forceinline__ f32x4 mfma16x16x32(bf16x8 a, bf16x8 b, f32x4 c) {
  return __builtin_amdgcn_mfma_f32_16x16x32_bf16(a, b, c, 0, 0, 0);
}

// async global->LDS, 16B per lane; LDS dest is wave-uniform base + lane*16
__device__ __forceinline__ void gll16(uint16_t* lds, const uint16_t* g) {
  __builtin_amdgcn_global_load_lds(
      (const __attribute__((address_space(1))) uint32_t*)g,
      (__attribute__((address_space(3))) uint32_t*)lds, 16, 0, 0);
}

// ---- T2-style granule swizzle ----
// LDS tile = [ROWS][4 granules of 8 bf16] (BK=32). Stored granule
// (row, s) holds global (row, kg = s ^ ((row>>1)&3)). gload_lds dest stays
// LINEAR (rule #21); the permutation lives in the per-lane GLOBAL source.
// Fragment read for (row, chunk l4) -> granule row*4 + (l4 ^ ((row>>1)&3)):
// a 16-lane group (fixed l4, rows l15=0..15) covers all 8 bank-quads 2x
// instead of 2 quads 8x (the measured 2.1M-conflict pattern).
__device__ __forceinline__ int fidx(int row, int l4) {
  return row * 4 + (l4 ^ ((row >> 1) & 3));
}

template <int ROWS>
__device__ __forceinline__ void stage32s(const uint16_t* __restrict__ src,
                                         uint16_t* lds, int tid) {
  const int wb = tid & 192;  // wave*64 granules
#pragma unroll
  for (int p = 0; p < ROWS / 64; ++p) {
    const int gi = p * 256 + tid;
    const int row = gi >> 2;
    const int kg = (gi & 3) ^ ((row >> 1) & 3);
    gll16(lds + (p * 256 + wb) * 8, src + row * UNITS + kg * 8);
  }
}

// ---- prep (fused): blocks [0,4096): h f32->bf16; [4096,8192): R -> RT bf16 ----
__global__ __launch_bounds__(256) void prep_kernel(const float* __restrict__ h32,
                                                   uint16_t* __restrict__ hbf,
                                                   const float* __restrict__ R,
                                                   uint16_t* __restrict__ RT) {
  __shared__ float t[32][33];
  const int b = blockIdx.x;
  if (b < 4096) {
    const int i = (b * 256 + threadIdx.x) * 4;
    float4 v = *(const float4*)(h32 + i);
    ushort4 o;
    o.x = f2bf(v.x); o.y = f2bf(v.y); o.z = f2bf(v.z); o.w = f2bf(v.w);
    *(ushort4*)(hbf + i) = o;
  } else {
    const int bb = b - 4096;
    const int n0 = (bb & 127) * 32, k0 = (bb >> 7) * 32;
    const int tx = threadIdx.x & 31, ty = threadIdx.x >> 5;
#pragma unroll
    for (int i = 0; i < 4; ++i)
      t[ty + i * 8][tx] = R[(size_t)(k0 + ty + i * 8) * FOURU + n0 + tx];
    __syncthreads();
#pragma unroll
    for (int i = 0; i < 4; ++i)
      RT[(size_t)(n0 + ty + i * 8) * UNITS + k0 + tx] = f2bf(t[tx][ty + i * 8]);
  }
}

// ---- unified GEMM: BM=64, BK=32, dbuf + gload_lds, 4 blocks/CU ----
// EPI 0: s1 BN=128, N=2048 (z cols [0,1024), r cols [1024,2048)) -> zb / rhb
// EPI 1: s2 BN=64: hh=tanh(+ch+b1); hn=z*h+(1-z)*hh -> h_out(f32) + hnb(bf16)
// EPI 2: s3 BN=64: o =tanh(+co+b2) -> o_out(f32)
// Grid is always (16,64)=1024 blocks; XCD-aware bijective remap inside.
template <int BN, int EPI>
__global__ __launch_bounds__(256, 4) void gemm_kernel(
    const uint16_t* __restrict__ abf, const uint16_t* __restrict__ bt,
    const int* __restrict__ idx, const float* __restrict__ kc,
    const float* __restrict__ bz, const float* __restrict__ bias,
    const float* __restrict__ h32, const uint16_t* __restrict__ hbf,
    const uint16_t* __restrict__ zb_in, float* __restrict__ out32,
    uint16_t* __restrict__ outbf, uint16_t* __restrict__ out2bf) {
  constexpr int NF = BN / 32;  // B frags per wave
  __shared__ uint16_t sA[2][64 * 32];
  __shared__ uint16_t sB[2][BN * 32];
  const int tid = threadIdx.x;
  const int lane = tid & 63, wave = tid >> 6;
  const int l15 = lane & 15, l4 = lane >> 4;
  // T1: nwg=1024, 8 XCDs, q=128; col-major decode -> each XCD holds ~2 B panels
  const int fid = blockIdx.y * 16 + blockIdx.x;
  const int nid = (fid & 7) * 128 + (fid >> 3);
  const int row0 = (nid & 63) * 64;
  const int col0 = (nid >> 6) * BN;
  const int wr = wave >> 1, wc = wave & 1;
  const uint16_t* pa = abf + (size_t)row0 * UNITS;
  const uint16_t* pb = bt + (size_t)col0 * UNITS;
  f32x4 acc[2][NF] = {};

  stage32s<64>(pa, sA[0], tid);
  stage32s<BN>(pb, sB[0], tid);
  __syncthreads();

  int cur = 0;
  for (int t = 0; t < 32; ++t) {
    if (t < 31) {  // issue next-tile loads before compute
      stage32s<64>(pa + (t + 1) * 32, sA[cur ^ 1], tid);
      stage32s<BN>(pb + (t + 1) * 32, sB[cur ^ 1], tid);
    }
    const bf16x8* A8 = (const bf16x8*)sA[cur];
    const bf16x8* B8 = (const bf16x8*)sB[cur];
    bf16x8 af[2], bf[NF];
#pragma unroll
    for (int m = 0; m < 2; ++m) af[m] = A8[fidx(wr * 32 + m * 16 + l15, l4)];
#pragma unroll
    for (int n = 0; n < NF; ++n)
      bf[n] = B8[fidx(wc * (BN / 2) + n * 16 + l15, l4)];
#pragma unroll
    for (int m = 0; m < 2; ++m)
#pragma unroll
      for (int n = 0; n < NF; ++n)
        acc[m][n] = mfma16x16x32(af[m], bf[n], acc[m][n]);
    __syncthreads();  // drains next-tile gload_lds; fences buffer swap
    cur ^= 1;
  }

#pragma unroll
  for (int m = 0; m < 2; ++m) {
#pragma unroll
    for (int q = 0; q < 4; ++q) {
      const int i = row0 + wr * 32 + m * 16 + l4 * 4 + q;
      const int ch = idx[i];
      const float* kcrow = kc + (size_t)ch * FOURU;
#pragma unroll
      for (int n = 0; n < NF; ++n) {
        const int jc = col0 + wc * (BN / 2) + n * 16 + l15;
        const float a = acc[m][n][q];
        if (EPI == 0) {
          if (jc < UNITS) {  // z gate (block-uniform: col0 multiple of 128)
            float z = fsig(a + kcrow[jc] + bz[jc]);
            outbf[(size_t)i * UNITS + jc] = f2bf(z);
          } else {  // r gate
            const int j = jc - UNITS;
            const size_t ij = (size_t)i * UNITS + j;
            float r = fsig(a + kcrow[jc] + bias[j]);
            out2bf[ij] = f2bf(r * bf2f(hbf[ij]));
          }
        } else if (EPI == 1) {
          const size_t ij = (size_t)i * UNITS + jc;
          float hh = tanhf(a + kcrow[2 * UNITS + jc] + bias[UNITS + jc]);
          float z = bf2f(zb_in[ij]);
          float hv = h32[ij];
          float hn = z * hv + (1.0f - z) * hh;
          out32[ij] = hn;
          outbf[ij] = f2bf(hn);
        } else {
          const size_t ij = (size_t)i * UNITS + jc;
          out32[ij] = tanhf(a + kcrow[3 * UNITS + jc] + bias[2 * UNITS + jc]);
        }
      }
    }
  }
}

extern "C" void kernel_launch(void* const* d_in, const int* in_sizes, int n_in,
                              void* d_out, int out_size, void* d_ws, size_t ws_size,
                              hipStream_t stream) {
  const int* idx = (const int*)d_in[0];
  const float* h32 = (const float*)d_in[1];
  const float* R = (const float*)d_in[2];
  const float* kc = (const float*)d_in[3];
  const float* bz = (const float*)d_in[4];
  const float* bias = (const float*)d_in[5];

  float* o_out = (float*)d_out;                  // 4M f32 (output o)
  float* h_out = o_out + (size_t)BATCH * UNITS;  // 4M f32 (output h)

  uint16_t* hbf = (uint16_t*)d_ws;               // bf16(h_tm1)   8 MB
  uint16_t* rt = hbf + (size_t)BATCH * UNITS;    // bf16(R^T)     8 MB
  uint16_t* rhb = rt + (size_t)FOURU * UNITS;    // bf16(r*h)     8 MB
  uint16_t* hnb = rhb + (size_t)BATCH * UNITS;   // bf16(h_new)   8 MB
  uint16_t* zbuf = hnb + (size_t)BATCH * UNITS;  // bf16(z)       8 MB

  prep_kernel<<<dim3(8192), 256, 0, stream>>>(h32, hbf, R, rt);

  // s1: N=2048 unified z|r GEMM, BN=128 -> grid (16,64)=1024
  gemm_kernel<128, 0><<<dim3(16, 64), 256, 0, stream>>>(
      hbf, rt, idx, kc, bz, bias, h32, hbf, nullptr, nullptr, zbuf, rhb);

  // s2: N=1024, BN=64 -> grid (16,64)=1024
  gemm_kernel<64, 1><<<dim3(16, 64), 256, 0, stream>>>(
      rhb, rt + (size_t)2 * UNITS * UNITS, idx, kc, bz, bias, h32, hbf, zbuf,
      h_out, hnb, nullptr);

  // s3: N=1024, BN=64 -> grid (16,64)=1024
  gemm_kernel<64, 2><<<dim3(16, 64), 256, 0, stream>>>(
      hnb, rt + (size_t)3 * UNITS * UNITS, idx, kc, bz, bias, nullptr, nullptr,
      nullptr, o_out, nullptr, nullptr);
}